// Round 8
// baseline (203.935 us; speedup 1.0000x reference)
//
#include <hip/hip_runtime.h>

#define SEQ 2048
#define NH 16
#define HD 64
#define DMODEL 1024

__device__ __forceinline__ unsigned int f2bf(float f) {
  // fp32 -> bf16 bits, round-to-nearest-even (finite inputs only)
  unsigned int u = __float_as_uint(f);
  return ((u + 0x7fffu + ((u >> 16) & 1u)) >> 16) & 0xffffu;
}

// packed fp32x2 -> bf16x2 (RNE via __bf16 cvt)
__device__ __forceinline__ unsigned int pk2bf(float a, float b) {
  unsigned short ua = __builtin_bit_cast(unsigned short, (__bf16)a);
  unsigned short ub = __builtin_bit_cast(unsigned short, (__bf16)b);
  return (unsigned int)ua | ((unsigned int)ub << 16);
}

typedef __bf16 bf16x8 __attribute__((ext_vector_type(8)));
typedef float f32x4 __attribute__((ext_vector_type(4)));

// async global->LDS, 16B per lane; LDS dest = wave-uniform base + lane*16
__device__ __forceinline__ void gl2lds16(const unsigned short* g, unsigned short* l) {
  __builtin_amdgcn_global_load_lds(
      (const __attribute__((address_space(1))) unsigned int*)g,
      (__attribute__((address_space(3))) unsigned int*)l, 16, 0, 0);
}

// one launch casts x + all four weight matrices to bf16
__global__ __launch_bounds__(256) void cast_all_kernel(
    const float* __restrict__ x, const float* __restrict__ wq,
    const float* __restrict__ wk, const float* __restrict__ wv,
    const float* __restrict__ wo,
    unsigned short* __restrict__ xb, unsigned short* __restrict__ wqb,
    unsigned short* __restrict__ wkb, unsigned short* __restrict__ wvb,
    unsigned short* __restrict__ wob) {
  int idx = blockIdx.x * 256 + threadIdx.x;
  if (idx >= 1048576) return;
  const float* src;
  unsigned short* dst;
  int off;
  if (idx < 524288) {
    src = x; dst = xb; off = idx;
  } else {
    int t = idx - 524288;
    int w = t >> 17;
    off = t & 131071;
    src = (w == 0) ? wq : (w == 1) ? wk : (w == 2) ? wv : wo;
    dst = (w == 0) ? wqb : (w == 1) ? wkb : (w == 2) ? wvb : wob;
  }
  const float4* p = reinterpret_cast<const float4*>(src) + (size_t)off * 2;
  float4 a = p[0], b = p[1];
  uint4 o;
  o.x = f2bf(a.x) | (f2bf(a.y) << 16);
  o.y = f2bf(a.z) | (f2bf(a.w) << 16);
  o.z = f2bf(b.x) | (f2bf(b.y) << 16);
  o.w = f2bf(b.z) | (f2bf(b.w) << 16);
  reinterpret_cast<uint4*>(dst)[off] = o;
}

// 128x128-tile GEMM, BK=64, global_load_lds staging, XOR-swizzled LDS chunks.
// MODE 0: fused QKV epilogue (cols 0..1023 Q *qscale, 1024..2047 K, 2048..3071 V^T).
// MODE 1: fp32 C[M][1024] + bias0 (out projection).
template <int MODE>
__global__ __launch_bounds__(256) void gemm128(
    const unsigned short* __restrict__ A, const unsigned short* __restrict__ B,
    const float* __restrict__ bias0, const float* __restrict__ bias1,
    const float* __restrict__ bias2, float* __restrict__ Cf,
    unsigned short* __restrict__ Qo, unsigned short* __restrict__ Ko,
    unsigned short* __restrict__ Vto, int Kdim) {
  __shared__ __align__(16) unsigned short As[128 * 64];
  __shared__ __align__(16) unsigned short Bs[128 * 64];
  const int tid = threadIdx.x;
  const int wave = tid >> 6, lane = tid & 63;
  const int wm = wave >> 1, wn = wave & 1;  // 2x2 waves -> 64x64 sub-tiles
  const int fr = lane & 15, quad = lane >> 4;
  const int fx = fr & 7;  // swizzle key for fragment reads
  const int n0 = blockIdx.x * 128, m0 = blockIdx.y * 128;

  // staging: lane -> (row = lane>>3, swizzled chunk = (lane&7) ^ ((lane>>3)&7))
  const int srowg = lane >> 3;
  const int schunk = (lane & 7) ^ (srowg & 7);
  const unsigned short* Abase =
      A + (size_t)(m0 + wave * 32 + srowg) * Kdim + schunk * 8;
  const unsigned short* Bbase =
      B + (size_t)(n0 + wave * 32 + srowg) * Kdim + schunk * 8;
  unsigned short* AsW = As + (wave * 32) * 64;
  unsigned short* BsW = Bs + (wave * 32) * 64;

  f32x4 acc[4][4];
#pragma unroll
  for (int mt = 0; mt < 4; ++mt)
#pragma unroll
    for (int nt = 0; nt < 4; ++nt) acc[mt][nt] = f32x4{0.f, 0.f, 0.f, 0.f};

  for (int k0 = 0; k0 < Kdim; k0 += 64) {
#pragma unroll
    for (int t = 0; t < 4; ++t) {
      gl2lds16(Abase + (size_t)(t * 8) * Kdim + k0, AsW + t * 8 * 64);
      gl2lds16(Bbase + (size_t)(t * 8) * Kdim + k0, BsW + t * 8 * 64);
    }
    __syncthreads();  // drains vmcnt(0): staged tile visible
#pragma unroll
    for (int ks = 0; ks < 2; ++ks) {
      bf16x8 af[4], bfv[4];
#pragma unroll
      for (int mt = 0; mt < 4; ++mt)
        af[mt] = *reinterpret_cast<const bf16x8*>(
            As + (wm * 64 + mt * 16 + fr) * 64 + ((ks * 4 + quad) ^ fx) * 8);
#pragma unroll
      for (int nt = 0; nt < 4; ++nt)
        bfv[nt] = *reinterpret_cast<const bf16x8*>(
            Bs + (wn * 64 + nt * 16 + fr) * 64 + ((ks * 4 + quad) ^ fx) * 8);
#pragma unroll
      for (int mt = 0; mt < 4; ++mt)
#pragma unroll
        for (int nt = 0; nt < 4; ++nt)
          acc[mt][nt] = __builtin_amdgcn_mfma_f32_16x16x32_bf16(
              af[mt], bfv[nt], acc[mt][nt], 0, 0, 0);
    }
    __syncthreads();
  }

  // epilogue. C/D: col = lane&15, row = quad*4+reg (m89/m91-verified).
  if (MODE == 0) {
    const int seg = n0 >> 10;  // uniform per block
    const float* bp = (seg == 0) ? bias0 : (seg == 1) ? bias1 : bias2;
    // Q pre-scaled by (1/sqrt(64)) * log2(e): attention works in exp2 domain
    const float scale = (seg == 0) ? 0.1803368809f : 1.0f;
    unsigned short* QK = (seg == 0) ? Qo : Ko;
#pragma unroll
    for (int nt = 0; nt < 4; ++nt) {
      const int c = (n0 + wn * 64 + nt * 16 + fr) & 1023;
      const int h = c >> 6, d = c & 63;
      const float bs = bp[c];
#pragma unroll
      for (int mt = 0; mt < 4; ++mt) {
        const int mbase = m0 + wm * 64 + mt * 16 + quad * 4;
        const int b = mbase >> 11, s0 = mbase & 2047;
        if (seg < 2) {
          unsigned short* dst = QK + (((size_t)(b * NH + h)) * SEQ + s0) * HD + d;
#pragma unroll
          for (int r = 0; r < 4; ++r)
            dst[(size_t)r * HD] = (unsigned short)f2bf((acc[mt][nt][r] + bs) * scale);
        } else {  // V^T: rows contiguous in s -> 8B store
          uint2 pk;
          pk.x = pk2bf(acc[mt][nt][0] + bs, acc[mt][nt][1] + bs);
          pk.y = pk2bf(acc[mt][nt][2] + bs, acc[mt][nt][3] + bs);
          *reinterpret_cast<uint2*>(
              Vto + (((size_t)(b * NH + h)) * HD + d) * SEQ + s0) = pk;
        }
      }
    }
  } else {
#pragma unroll
    for (int nt = 0; nt < 4; ++nt) {
      const int cg = n0 + wn * 64 + nt * 16 + fr;
      const float bs = bias0[cg];
#pragma unroll
      for (int mt = 0; mt < 4; ++mt) {
        const int mbase = m0 + wm * 64 + mt * 16 + quad * 4;
#pragma unroll
        for (int r = 0; r < 4; ++r)
          Cf[(size_t)(mbase + r) * DMODEL + cg] = acc[mt][nt][r] + bs;
      }
    }
  }
}

// MFMA flash attention, exp2 domain. R5 structure (4-wave blocks, grid 512,
// equal-work tile pairs {31-g, g}, K/V staged once per j-iter for all 4 waves)
// with R7's async swizzled staging: global_load_lds DMA into XOR-swizzled
// LDS (pitch 64): LDS[r][c] = G[r][c^(r&7)]; frag reads use chunk c^(fr&7).
// S^T = K*Q^T then O^T = V^T*P^T: lane's C-col is its own Q row.
__global__ __launch_bounds__(256) void attn_mfma_kernel(
    const unsigned short* __restrict__ Qg, const unsigned short* __restrict__ Kg,
    const unsigned short* __restrict__ Vtg, const int* __restrict__ mask,
    unsigned short* __restrict__ concat) {
  const int g = blockIdx.x >> 5;        // 0..15 (ascending -> heavy blocks first)
  const int bh = blockIdx.x & 31;
  const int b = bh >> 4, h = bh & 15;
  const int tid = threadIdx.x;
  const int wave = tid >> 6, lane = tid & 63;
  const int quad = lane >> 4, fr = lane & 15;
  const int ibA = 31 - g, ibB = g;

  __shared__ __align__(16) unsigned short Ks[64 * 64];   // swizzled, pitch 64
  __shared__ __align__(16) unsigned short Vts[64 * 64];  // swizzled, pitch 64
  __shared__ unsigned short Pt[4][2][16][72];            // [wave][tile], pitch 72

  const unsigned short* Qb = Qg + ((size_t)bh * SEQ) * HD;
  const unsigned short* Kb = Kg + ((size_t)bh * SEQ) * HD;
  const unsigned short* Vtb = Vtg + ((size_t)bh * HD) * SEQ;
  const int* maskb = mask + b * SEQ;

  // pad-mask tile bitmap via wave ballot: lane covers ints [lane*32, lane*32+32)
  // -> tile jc covered by ballot bits {2jc, 2jc+1}
  bool badl = false;
  {
    const int4* mp4 = reinterpret_cast<const int4*>(maskb);
#pragma unroll
    for (int u = 0; u < 8; ++u) {
      int4 v = mp4[lane * 8 + u];
      badl |= !(v.x && v.y && v.z && v.w);
    }
  }
  const unsigned long long bm = __ballot(badl);

  const int irA = ibA * 64 + wave * 16 + fr;
  const int irB = ibB * 64 + wave * 16 + fr;
  const bf16x8 qA0 = *reinterpret_cast<const bf16x8*>(Qb + (size_t)irA * HD + quad * 8);
  const bf16x8 qA1 = *reinterpret_cast<const bf16x8*>(Qb + (size_t)irA * HD + quad * 8 + 32);
  const bf16x8 qB0 = *reinterpret_cast<const bf16x8*>(Qb + (size_t)irB * HD + quad * 8);
  const bf16x8 qB1 = *reinterpret_cast<const bf16x8*>(Qb + (size_t)irB * HD + quad * 8 + 32);
  const int padA = maskb[irA], padB = maskb[irB];

  f32x4 oA[4], oB[4];
#pragma unroll
  for (int vt = 0; vt < 4; ++vt) { oA[vt] = f32x4{0,0,0,0}; oB[vt] = f32x4{0,0,0,0}; }
  // init -1e20 (not -1e30): all-masked tiles then give exp2(-1e30+1e20)=0 safely
  float mA = -1e20f, lA = 0.f, mB = -1e20f, lB = 0.f;

  // staging: wave stages rows [wave*16, wave*16+16) of BOTH K and V^T tiles,
  // 2 DMA calls each (8 rows/call). lane -> (row=lane>>3, chunk=(lane&7)^(row&7)).
  const int srowg = lane >> 3;
  const int schunk = (lane & 7) ^ (srowg & 7);
  const unsigned short* Ksrc = Kb + (size_t)(wave * 16 + srowg) * HD + schunk * 8;
  const unsigned short* Vsrc = Vtb + (size_t)(wave * 16 + srowg) * SEQ + schunk * 8;
  unsigned short* KsW = Ks + (wave * 16) * 64;
  unsigned short* VtsW = Vts + (wave * 16) * 64;
  const int cA0 = (quad ^ (fr & 7)) * 8;        // frag chunk for k in [0,32)
  const int cA1 = ((quad + 4) ^ (fr & 7)) * 8;  // frag chunk for k in [32,64)

  for (int jc = 0; jc <= ibA; ++jc) {
    const int j0 = jc * 64;
#pragma unroll
    for (int t = 0; t < 2; ++t) {
      gl2lds16(Ksrc + (size_t)(j0 + t * 8) * HD, KsW + t * 8 * 64);
      gl2lds16(Vsrc + (size_t)(t * 8) * SEQ + j0, VtsW + t * 8 * 64);
    }
    __syncthreads();  // drains vmcnt: staged tiles visible

    const bool doB = (jc <= ibB);
    const bool tb = ((bm >> (2 * jc)) & 3ull) != 0ull;

    // S^T strips for both i-tiles, sharing the Ks fragment reads
    f32x4 stA[4], stB[4];
#pragma unroll
    for (int jt = 0; jt < 4; ++jt) {
      bf16x8 ka0 = *reinterpret_cast<const bf16x8*>(&Ks[(jt * 16 + fr) * 64 + cA0]);
      bf16x8 ka1 = *reinterpret_cast<const bf16x8*>(&Ks[(jt * 16 + fr) * 64 + cA1]);
      stA[jt] = f32x4{0,0,0,0};
      stA[jt] = __builtin_amdgcn_mfma_f32_16x16x32_bf16(ka0, qA0, stA[jt], 0, 0, 0);
      stA[jt] = __builtin_amdgcn_mfma_f32_16x16x32_bf16(ka1, qA1, stA[jt], 0, 0, 0);
      if (doB) {
        stB[jt] = f32x4{0,0,0,0};
        stB[jt] = __builtin_amdgcn_mfma_f32_16x16x32_bf16(ka0, qB0, stB[jt], 0, 0, 0);
        stB[jt] = __builtin_amdgcn_mfma_f32_16x16x32_bf16(ka1, qB1, stB[jt], 0, 0, 0);
      }
    }

    if (tb) {  // rare: per-element pad-col mask
      const int4* mp = reinterpret_cast<const int4*>(maskb + j0);
#pragma unroll
      for (int jt = 0; jt < 4; ++jt) {
        const int4 mv = mp[jt * 4 + quad];
        if (mv.x == 0) { stA[jt][0] = -1e30f; if (doB) stB[jt][0] = -1e30f; }
        if (mv.y == 0) { stA[jt][1] = -1e30f; if (doB) stB[jt][1] = -1e30f; }
        if (mv.z == 0) { stA[jt][2] = -1e30f; if (doB) stB[jt][2] = -1e30f; }
        if (mv.w == 0) { stA[jt][3] = -1e30f; if (doB) stB[jt][3] = -1e30f; }
      }
    }
    if (jc == ibA) {  // causal mask, tile A
#pragma unroll
      for (int jt = 0; jt < 4; ++jt) {
        const int jb = j0 + jt * 16 + quad * 4;
#pragma unroll
        for (int r = 0; r < 4; ++r)
          if (jb + r > irA) stA[jt][r] = -1e30f;
      }
    }
    if (doB && jc == ibB) {  // causal mask, tile B
#pragma unroll
      for (int jt = 0; jt < 4; ++jt) {
        const int jb = j0 + jt * 16 + quad * 4;
#pragma unroll
        for (int r = 0; r < 4; ++r)
          if (jb + r > irB) stB[jt][r] = -1e30f;
      }
    }

    // ---- softmax + Pt pack, tile A ----
    {
      float tmax = -1e30f;
#pragma unroll
      for (int jt = 0; jt < 4; ++jt)
#pragma unroll
        for (int r = 0; r < 4; ++r) tmax = fmaxf(tmax, stA[jt][r]);
      tmax = fmaxf(tmax, __shfl_xor(tmax, 16));
      tmax = fmaxf(tmax, __shfl_xor(tmax, 32));
      const bool upd = __ballot(tmax > mA) != 0ull;  // wave-uniform
      float corr = 1.f;
      if (upd) { const float mn = fmaxf(mA, tmax); corr = __builtin_amdgcn_exp2f(mA - mn); mA = mn; }
      float lloc = 0.f;
#pragma unroll
      for (int jt = 0; jt < 4; ++jt) {
        float p0 = __builtin_amdgcn_exp2f(stA[jt][0] - mA);
        float p1 = __builtin_amdgcn_exp2f(stA[jt][1] - mA);
        float p2 = __builtin_amdgcn_exp2f(stA[jt][2] - mA);
        float p3 = __builtin_amdgcn_exp2f(stA[jt][3] - mA);
        lloc += (p0 + p1) + (p2 + p3);
        uint2 pk; pk.x = pk2bf(p0, p1); pk.y = pk2bf(p2, p3);
        *reinterpret_cast<uint2*>(&Pt[wave][0][fr][jt * 16 + quad * 4]) = pk;
      }
      lloc += __shfl_xor(lloc, 16);
      lloc += __shfl_xor(lloc, 32);
      if (upd) {
        lA = lA * corr + lloc;
#pragma unroll
        for (int vt = 0; vt < 4; ++vt) {
          oA[vt][0] *= corr; oA[vt][1] *= corr; oA[vt][2] *= corr; oA[vt][3] *= corr;
        }
      } else lA += lloc;
    }
    // ---- softmax + Pt pack, tile B ----
    if (doB) {
      float tmax = -1e30f;
#pragma unroll
      for (int jt = 0; jt < 4; ++jt)
#pragma unroll
        for (int r = 0; r < 4; ++r) tmax = fmaxf(tmax, stB[jt][r]);
      tmax = fmaxf(tmax, __shfl_xor(tmax, 16));
      tmax = fmaxf(tmax, __shfl_xor(tmax, 32));
      const bool upd = __ballot(tmax > mB) != 0ull;
      float corr = 1.f;
      if (upd) { const float mn = fmaxf(mB, tmax); corr = __builtin_amdgcn_exp2f(mB - mn); mB = mn; }
      float lloc = 0.f;
#pragma unroll
      for (int jt = 0; jt < 4; ++jt) {
        float p0 = __builtin_amdgcn_exp2f(stB[jt][0] - mB);
        float p1 = __builtin_amdgcn_exp2f(stB[jt][1] - mB);
        float p2 = __builtin_amdgcn_exp2f(stB[jt][2] - mB);
        float p3 = __builtin_amdgcn_exp2f(stB[jt][3] - mB);
        lloc += (p0 + p1) + (p2 + p3);
        uint2 pk; pk.x = pk2bf(p0, p1); pk.y = pk2bf(p2, p3);
        *reinterpret_cast<uint2*>(&Pt[wave][1][fr][jt * 16 + quad * 4]) = pk;
      }
      lloc += __shfl_xor(lloc, 16);
      lloc += __shfl_xor(lloc, 32);
      if (upd) {
        lB = lB * corr + lloc;
#pragma unroll
        for (int vt = 0; vt < 4; ++vt) {
          oB[vt][0] *= corr; oB[vt][1] *= corr; oB[vt][2] *= corr; oB[vt][3] *= corr;
        }
      } else lB += lloc;
    }

    // ---- O^T += V^T * P^T, sharing Vts fragment reads ----
    bf16x8 paA0 = *reinterpret_cast<const bf16x8*>(&Pt[wave][0][fr][quad * 8]);
    bf16x8 paA1 = *reinterpret_cast<const bf16x8*>(&Pt[wave][0][fr][quad * 8 + 32]);
    bf16x8 paB0, paB1;
    if (doB) {
      paB0 = *reinterpret_cast<const bf16x8*>(&Pt[wave][1][fr][quad * 8]);
      paB1 = *reinterpret_cast<const bf16x8*>(&Pt[wave][1][fr][quad * 8 + 32]);
    }
#pragma unroll
    for (int vt = 0; vt < 4; ++vt) {
      bf16x8 vb0 = *reinterpret_cast<const bf16x8*>(&Vts[(vt * 16 + fr) * 64 + cA0]);
      bf16x8 vb1 = *reinterpret_cast<const bf16x8*>(&Vts[(vt * 16 + fr) * 64 + cA1]);
      oA[vt] = __builtin_amdgcn_mfma_f32_16x16x32_bf16(vb0, paA0, oA[vt], 0, 0, 0);
      oA[vt] = __builtin_amdgcn_mfma_f32_16x16x32_bf16(vb1, paA1, oA[vt], 0, 0, 0);
      if (doB) {
        oB[vt] = __builtin_amdgcn_mfma_f32_16x16x32_bf16(vb0, paB0, oB[vt], 0, 0, 0);
        oB[vt] = __builtin_amdgcn_mfma_f32_16x16x32_bf16(vb1, paB1, oB[vt], 0, 0, 0);
      }
    }
    __syncthreads();  // protect Ks/Vts before next stage
  }

  // epilogue: O^T[v][i=fr] / l_i -> concat bf16 [b,s,h*64]
  {
    const float inv = (padA != 0 && lA > 0.f) ? 1.f / lA : 0.f;
    unsigned short* orow = concat + ((size_t)(b * SEQ + irA)) * DMODEL + h * HD;
#pragma unroll
    for (int vt = 0; vt < 4; ++vt) {
      uint2 pk;
      pk.x = pk2bf(oA[vt][0] * inv, oA[vt][1] * inv);
      pk.y = pk2bf(oA[vt][2] * inv, oA[vt][3] * inv);
      *reinterpret_cast<uint2*>(orow + vt * 16 + quad * 4) = pk;
    }
  }
  {
    const float inv = (padB != 0 && lB > 0.f) ? 1.f / lB : 0.f;
    unsigned short* orow = concat + ((size_t)(b * SEQ + irB)) * DMODEL + h * HD;
#pragma unroll
    for (int vt = 0; vt < 4; ++vt) {
      uint2 pk;
      pk.x = pk2bf(oB[vt][0] * inv, oB[vt][1] * inv);
      pk.y = pk2bf(oB[vt][2] * inv, oB[vt][3] * inv);
      *reinterpret_cast<uint2*>(orow + vt * 16 + quad * 4) = pk;
    }
  }
}

extern "C" void kernel_launch(void* const* d_in, const int* in_sizes, int n_in,
                              void* d_out, int out_size, void* d_ws, size_t ws_size,
                              hipStream_t stream) {
  (void)in_sizes; (void)n_in; (void)out_size;
  const float* x  = (const float*)d_in[0];
  const int* mask = (const int*)d_in[1];
  const float* Wq = (const float*)d_in[2];
  const float* bq = (const float*)d_in[3];
  const float* Wk = (const float*)d_in[4];
  const float* bk = (const float*)d_in[5];
  const float* Wv = (const float*)d_in[6];
  const float* bv = (const float*)d_in[7];
  const float* Wo = (const float*)d_in[8];
  const float* bo = (const float*)d_in[9];
  float* out = (float*)d_out;

  char* ws = (char*)d_ws;
  if (ws_size < (48ull << 20)) return;
  unsigned short* xb  = (unsigned short*)(ws);                 // 8 MB x bf16 [4096][1024]
  unsigned short* wqb = (unsigned short*)(ws + (8ull  << 20)); // wq|wk|wv contiguous ->
  unsigned short* wkb = (unsigned short*)(ws + (10ull << 20)); //   [3072][1024] B matrix
  unsigned short* wvb = (unsigned short*)(ws + (12ull << 20));
  unsigned short* wob = (unsigned short*)(ws + (14ull << 20));
  unsigned short* Qb  = (unsigned short*)(ws + (16ull << 20)); // 8 MB [b,h,s,64] (xscale)
  unsigned short* Kb  = (unsigned short*)(ws + (24ull << 20)); // 8 MB [b,h,s,64]
  unsigned short* Vtb = (unsigned short*)(ws + (32ull << 20)); // 8 MB [b,h,64,s]
  unsigned short* cb  = (unsigned short*)(ws + (40ull << 20)); // 8 MB concat bf16

  cast_all_kernel<<<4096, 256, 0, stream>>>(x, Wq, Wk, Wv, Wo, xb, wqb, wkb, wvb, wob);

  // fused QKV projection: B = [wq; wk; wv] = [3072][1024]
  gemm128<0><<<dim3(24, 32), 256, 0, stream>>>(xb, wqb, bq, bk, bv,
                                               nullptr, Qb, Kb, Vtb, 1024);

  attn_mfma_kernel<<<512, 256, 0, stream>>>(Qb, Kb, Vtb, mask, cb);

  gemm128<1><<<dim3(8, 32), 256, 0, stream>>>(cb, wob, bo, nullptr, nullptr,
                                              out, nullptr, nullptr, nullptr, 1024);
}

// Round 9
// 197.839 us; speedup vs baseline: 1.0308x; 1.0308x over previous
//
#include <hip/hip_runtime.h>

#define SEQ 2048
#define NH 16
#define HD 64
#define DMODEL 1024

__device__ __forceinline__ unsigned int f2bf(float f) {
  // fp32 -> bf16 bits, round-to-nearest-even (finite inputs only)
  unsigned int u = __float_as_uint(f);
  return ((u + 0x7fffu + ((u >> 16) & 1u)) >> 16) & 0xffffu;
}

// packed fp32x2 -> bf16x2 (RNE via __bf16 cvt)
__device__ __forceinline__ unsigned int pk2bf(float a, float b) {
  unsigned short ua = __builtin_bit_cast(unsigned short, (__bf16)a);
  unsigned short ub = __builtin_bit_cast(unsigned short, (__bf16)b);
  return (unsigned int)ua | ((unsigned int)ub << 16);
}

typedef __bf16 bf16x8 __attribute__((ext_vector_type(8)));
typedef float f32x4 __attribute__((ext_vector_type(4)));

// async global->LDS, 16B per lane; LDS dest = wave-uniform base + lane*16
__device__ __forceinline__ void gl2lds16(const unsigned short* g, unsigned short* l) {
  __builtin_amdgcn_global_load_lds(
      (const __attribute__((address_space(1))) unsigned int*)g,
      (__attribute__((address_space(3))) unsigned int*)l, 16, 0, 0);
}

// one launch casts x + all four weight matrices to bf16
__global__ __launch_bounds__(256) void cast_all_kernel(
    const float* __restrict__ x, const float* __restrict__ wq,
    const float* __restrict__ wk, const float* __restrict__ wv,
    const float* __restrict__ wo,
    unsigned short* __restrict__ xb, unsigned short* __restrict__ wqb,
    unsigned short* __restrict__ wkb, unsigned short* __restrict__ wvb,
    unsigned short* __restrict__ wob) {
  int idx = blockIdx.x * 256 + threadIdx.x;
  if (idx >= 1048576) return;
  const float* src;
  unsigned short* dst;
  int off;
  if (idx < 524288) {
    src = x; dst = xb; off = idx;
  } else {
    int t = idx - 524288;
    int w = t >> 17;
    off = t & 131071;
    src = (w == 0) ? wq : (w == 1) ? wk : (w == 2) ? wv : wo;
    dst = (w == 0) ? wqb : (w == 1) ? wkb : (w == 2) ? wvb : wob;
  }
  const float4* p = reinterpret_cast<const float4*>(src) + (size_t)off * 2;
  float4 a = p[0], b = p[1];
  uint4 o;
  o.x = f2bf(a.x) | (f2bf(a.y) << 16);
  o.y = f2bf(a.z) | (f2bf(a.w) << 16);
  o.z = f2bf(b.x) | (f2bf(b.y) << 16);
  o.w = f2bf(b.z) | (f2bf(b.w) << 16);
  reinterpret_cast<uint4*>(dst)[off] = o;
}

// 128x128-tile GEMM, BK=64, global_load_lds staging, XOR-swizzled LDS chunks.
// MODE 0: fused QKV epilogue (cols 0..1023 Q *qscale, 1024..2047 K, 2048..3071 V^T).
// MODE 1: fp32 C[M][1024] + bias0 (out projection).
template <int MODE>
__global__ __launch_bounds__(256) void gemm128(
    const unsigned short* __restrict__ A, const unsigned short* __restrict__ B,
    const float* __restrict__ bias0, const float* __restrict__ bias1,
    const float* __restrict__ bias2, float* __restrict__ Cf,
    unsigned short* __restrict__ Qo, unsigned short* __restrict__ Ko,
    unsigned short* __restrict__ Vto, int Kdim) {
  __shared__ __align__(16) unsigned short As[128 * 64];
  __shared__ __align__(16) unsigned short Bs[128 * 64];
  const int tid = threadIdx.x;
  const int wave = tid >> 6, lane = tid & 63;
  const int wm = wave >> 1, wn = wave & 1;  // 2x2 waves -> 64x64 sub-tiles
  const int fr = lane & 15, quad = lane >> 4;
  const int fx = fr & 7;  // swizzle key for fragment reads
  const int n0 = blockIdx.x * 128, m0 = blockIdx.y * 128;

  // staging: lane -> (row = lane>>3, swizzled chunk = (lane&7) ^ ((lane>>3)&7))
  const int srowg = lane >> 3;
  const int schunk = (lane & 7) ^ (srowg & 7);
  const unsigned short* Abase =
      A + (size_t)(m0 + wave * 32 + srowg) * Kdim + schunk * 8;
  const unsigned short* Bbase =
      B + (size_t)(n0 + wave * 32 + srowg) * Kdim + schunk * 8;
  unsigned short* AsW = As + (wave * 32) * 64;
  unsigned short* BsW = Bs + (wave * 32) * 64;

  f32x4 acc[4][4];
#pragma unroll
  for (int mt = 0; mt < 4; ++mt)
#pragma unroll
    for (int nt = 0; nt < 4; ++nt) acc[mt][nt] = f32x4{0.f, 0.f, 0.f, 0.f};

  for (int k0 = 0; k0 < Kdim; k0 += 64) {
#pragma unroll
    for (int t = 0; t < 4; ++t) {
      gl2lds16(Abase + (size_t)(t * 8) * Kdim + k0, AsW + t * 8 * 64);
      gl2lds16(Bbase + (size_t)(t * 8) * Kdim + k0, BsW + t * 8 * 64);
    }
    __syncthreads();  // drains vmcnt(0): staged tile visible
#pragma unroll
    for (int ks = 0; ks < 2; ++ks) {
      bf16x8 af[4], bfv[4];
#pragma unroll
      for (int mt = 0; mt < 4; ++mt)
        af[mt] = *reinterpret_cast<const bf16x8*>(
            As + (wm * 64 + mt * 16 + fr) * 64 + ((ks * 4 + quad) ^ fx) * 8);
#pragma unroll
      for (int nt = 0; nt < 4; ++nt)
        bfv[nt] = *reinterpret_cast<const bf16x8*>(
            Bs + (wn * 64 + nt * 16 + fr) * 64 + ((ks * 4 + quad) ^ fx) * 8);
#pragma unroll
      for (int mt = 0; mt < 4; ++mt)
#pragma unroll
        for (int nt = 0; nt < 4; ++nt)
          acc[mt][nt] = __builtin_amdgcn_mfma_f32_16x16x32_bf16(
              af[mt], bfv[nt], acc[mt][nt], 0, 0, 0);
    }
    __syncthreads();
  }

  // epilogue. C/D: col = lane&15, row = quad*4+reg (m89/m91-verified).
  if (MODE == 0) {
    const int seg = n0 >> 10;  // uniform per block
    const float* bp = (seg == 0) ? bias0 : (seg == 1) ? bias1 : bias2;
    // Q pre-scaled by (1/sqrt(64)) * log2(e): attention works in exp2 domain
    const float scale = (seg == 0) ? 0.1803368809f : 1.0f;
    unsigned short* QK = (seg == 0) ? Qo : Ko;
#pragma unroll
    for (int nt = 0; nt < 4; ++nt) {
      const int c = (n0 + wn * 64 + nt * 16 + fr) & 1023;
      const int h = c >> 6, d = c & 63;
      const float bs = bp[c];
#pragma unroll
      for (int mt = 0; mt < 4; ++mt) {
        const int mbase = m0 + wm * 64 + mt * 16 + quad * 4;
        const int b = mbase >> 11, s0 = mbase & 2047;
        if (seg < 2) {
          unsigned short* dst = QK + (((size_t)(b * NH + h)) * SEQ + s0) * HD + d;
#pragma unroll
          for (int r = 0; r < 4; ++r)
            dst[(size_t)r * HD] = (unsigned short)f2bf((acc[mt][nt][r] + bs) * scale);
        } else {  // V^T: rows contiguous in s -> 8B store
          uint2 pk;
          pk.x = pk2bf(acc[mt][nt][0] + bs, acc[mt][nt][1] + bs);
          pk.y = pk2bf(acc[mt][nt][2] + bs, acc[mt][nt][3] + bs);
          *reinterpret_cast<uint2*>(
              Vto + (((size_t)(b * NH + h)) * HD + d) * SEQ + s0) = pk;
        }
      }
    }
  } else {
#pragma unroll
    for (int nt = 0; nt < 4; ++nt) {
      const int cg = n0 + wn * 64 + nt * 16 + fr;
      const float bs = bias0[cg];
#pragma unroll
      for (int mt = 0; mt < 4; ++mt) {
        const int mbase = m0 + wm * 64 + mt * 16 + quad * 4;
#pragma unroll
        for (int r = 0; r < 4; ++r)
          Cf[(size_t)(mbase + r) * DMODEL + cg] = acc[mt][nt][r] + bs;
      }
    }
  }
}

// MFMA flash attention, exp2 domain. Single i-tile per block, grid 1024,
// 4 blocks/CU resident (LDS exactly 40960 B, VGPR capped via launch_bounds).
// Dispatch-class balance: bid = w*256 + (gg*32+bh); ib(w,gg) in
// {31-gg, gg, 23-gg, 8+gg} -> every stride-256 class sums to 62 passes.
// Double-buffered async DMA staging (XOR-swizzled, pitch 64), ONE barrier/iter:
// barrier publishes DMA[jc] (issued last iter), then DMA[jc+1] issues into the
// other buffer and hides behind compute[jc].
// S^T = K*Q^T then O^T = V^T*P^T: lane's C-col is its own Q row.
__global__ __launch_bounds__(256, 4) void attn_mfma_kernel(
    const unsigned short* __restrict__ Qg, const unsigned short* __restrict__ Kg,
    const unsigned short* __restrict__ Vtg, const int* __restrict__ mask,
    unsigned short* __restrict__ concat) {
  const int w = blockIdx.x >> 8;        // phase 0..3
  const int c = blockIdx.x & 255;
  const int gg = c >> 5;                // 0..7
  const int bh = c & 31;
  const int ib = (w == 0) ? (31 - gg) : (w == 1) ? gg : (w == 2) ? (23 - gg) : (8 + gg);
  const int b = bh >> 4, h = bh & 15;
  const int tid = threadIdx.x;
  const int wave = tid >> 6, lane = tid & 63;
  const int quad = lane >> 4, fr = lane & 15;
  const int fx = fr & 7;

  __shared__ __align__(16) unsigned short Ks[2][64 * 64];   // swizzled, pitch 64
  __shared__ __align__(16) unsigned short Vts[2][64 * 64];  // swizzled, pitch 64
  __shared__ __align__(16) unsigned short Pt[4][16 * 64];   // swizzled, wave-private

  const unsigned short* Qb = Qg + ((size_t)bh * SEQ) * HD;
  const unsigned short* Kb = Kg + ((size_t)bh * SEQ) * HD;
  const unsigned short* Vtb = Vtg + ((size_t)bh * HD) * SEQ;
  const int* maskb = mask + b * SEQ;

  // pad-mask tile bitmap via wave ballot: lane covers ints [lane*32, lane*32+32)
  // -> tile jc covered by ballot bits {2jc, 2jc+1}
  bool badl = false;
  {
    const int4* mp4 = reinterpret_cast<const int4*>(maskb);
#pragma unroll
    for (int u = 0; u < 8; ++u) {
      int4 v = mp4[lane * 8 + u];
      badl |= !(v.x && v.y && v.z && v.w);
    }
  }
  const unsigned long long bm = __ballot(badl);

  const int ir = ib * 64 + wave * 16 + fr;  // this lane's Q row (softmax owner)
  const bf16x8 q0 = *reinterpret_cast<const bf16x8*>(Qb + (size_t)ir * HD + quad * 8);
  const bf16x8 q1 = *reinterpret_cast<const bf16x8*>(Qb + (size_t)ir * HD + quad * 8 + 32);
  const int padi = maskb[ir];

  f32x4 o[4];
#pragma unroll
  for (int vt = 0; vt < 4; ++vt) o[vt] = f32x4{0.f, 0.f, 0.f, 0.f};
  // init -1e20 (not -1e30): all-masked tiles then give exp2(-1e30+1e20)=0 safely
  float mr = -1e20f, lr = 0.f;

  // staging: wave stages rows [wave*16, wave*16+16) of K and V^T tiles,
  // 2 DMA calls each. lane -> (row=lane>>3, chunk=(lane&7)^(row&7)).
  const int srowg = lane >> 3;
  const int schunk = (lane & 7) ^ (srowg & 7);
  const unsigned short* Ksrc = Kb + (size_t)(wave * 16 + srowg) * HD + schunk * 8;
  const unsigned short* Vsrc = Vtb + (size_t)(wave * 16 + srowg) * SEQ + schunk * 8;
  const int cA0 = (quad ^ fx) * 8;        // frag chunk for k in [0,32)
  const int cA1 = ((quad + 4) ^ fx) * 8;  // frag chunk for k in [32,64)
  unsigned short* PtW = Pt[wave];

  // pre-issue DMA for jc=0 into buffer 0
  {
    unsigned short* KsW = Ks[0] + (wave * 16) * 64;
    unsigned short* VtsW = Vts[0] + (wave * 16) * 64;
#pragma unroll
    for (int t = 0; t < 2; ++t) {
      gl2lds16(Ksrc + (size_t)(t * 8) * HD, KsW + t * 8 * 64);
      gl2lds16(Vsrc + (size_t)(t * 8) * SEQ, VtsW + t * 8 * 64);
    }
  }

  for (int jc = 0; jc <= ib; ++jc) {
    __syncthreads();  // drains DMA[jc] (vmcnt) + guards buffer reuse
    if (jc < ib) {    // prefetch next tile into the other buffer
      const int jn = (jc + 1) * 64;
      unsigned short* KsW = Ks[(jc + 1) & 1] + (wave * 16) * 64;
      unsigned short* VtsW = Vts[(jc + 1) & 1] + (wave * 16) * 64;
#pragma unroll
      for (int t = 0; t < 2; ++t) {
        gl2lds16(Ksrc + (size_t)(jn + t * 8) * HD, KsW + t * 8 * 64);
        gl2lds16(Vsrc + (size_t)(t * 8) * SEQ + jn, VtsW + t * 8 * 64);
      }
    }
    const unsigned short* Kcur = Ks[jc & 1];
    const unsigned short* Vcur = Vts[jc & 1];
    const int j0 = jc * 64;
    const bool tb = ((bm >> (2 * jc)) & 3ull) != 0ull;

    // S^T strip: C[m=j][n=i=fr]
    f32x4 st[4];
#pragma unroll
    for (int jt = 0; jt < 4; ++jt) {
      bf16x8 ka0 = *reinterpret_cast<const bf16x8*>(&Kcur[(jt * 16 + fr) * 64 + cA0]);
      bf16x8 ka1 = *reinterpret_cast<const bf16x8*>(&Kcur[(jt * 16 + fr) * 64 + cA1]);
      st[jt] = f32x4{0.f, 0.f, 0.f, 0.f};
      st[jt] = __builtin_amdgcn_mfma_f32_16x16x32_bf16(ka0, q0, st[jt], 0, 0, 0);
      st[jt] = __builtin_amdgcn_mfma_f32_16x16x32_bf16(ka1, q1, st[jt], 0, 0, 0);
    }

    if (tb) {  // rare: per-element pad-col mask
      const int4* mp = reinterpret_cast<const int4*>(maskb + j0);
#pragma unroll
      for (int jt = 0; jt < 4; ++jt) {
        const int4 mv = mp[jt * 4 + quad];
        if (mv.x == 0) st[jt][0] = -1e30f;
        if (mv.y == 0) st[jt][1] = -1e30f;
        if (mv.z == 0) st[jt][2] = -1e30f;
        if (mv.w == 0) st[jt][3] = -1e30f;
      }
    }
    if (jc == ib) {  // diagonal tile: causal mask
#pragma unroll
      for (int jt = 0; jt < 4; ++jt) {
        const int jb = j0 + jt * 16 + quad * 4;
#pragma unroll
        for (int r = 0; r < 4; ++r)
          if (jb + r > ir) st[jt][r] = -1e30f;
      }
    }

    // online softmax for row i=fr (state replicated across quads)
    float tmax = -1e30f;
#pragma unroll
    for (int jt = 0; jt < 4; ++jt)
#pragma unroll
      for (int r = 0; r < 4; ++r) tmax = fmaxf(tmax, st[jt][r]);
    tmax = fmaxf(tmax, __shfl_xor(tmax, 16));
    tmax = fmaxf(tmax, __shfl_xor(tmax, 32));
    const bool upd = __ballot(tmax > mr) != 0ull;  // wave-uniform
    float corr = 1.f;
    if (upd) { const float mn = fmaxf(mr, tmax); corr = __builtin_amdgcn_exp2f(mr - mn); mr = mn; }
    float lloc = 0.f;
#pragma unroll
    for (int jt = 0; jt < 4; ++jt) {
      float p0 = __builtin_amdgcn_exp2f(st[jt][0] - mr);
      float p1 = __builtin_amdgcn_exp2f(st[jt][1] - mr);
      float p2 = __builtin_amdgcn_exp2f(st[jt][2] - mr);
      float p3 = __builtin_amdgcn_exp2f(st[jt][3] - mr);
      lloc += (p0 + p1) + (p2 + p3);
      // P (bf16) -> swizzled Pt strip: logical chunk lc = 2*jt + (quad>>1),
      // physical chunk = lc ^ (fr&7), sub-offset (quad&1)*4 shorts
      uint2 pk; pk.x = pk2bf(p0, p1); pk.y = pk2bf(p2, p3);
      const int pc = (2 * jt + (quad >> 1)) ^ fx;
      *reinterpret_cast<uint2*>(&PtW[fr * 64 + pc * 8 + (quad & 1) * 4]) = pk;
    }
    lloc += __shfl_xor(lloc, 16);
    lloc += __shfl_xor(lloc, 32);
    if (upd) {
      lr = lr * corr + lloc;
#pragma unroll
      for (int vt = 0; vt < 4; ++vt) {
        o[vt][0] *= corr; o[vt][1] *= corr; o[vt][2] *= corr; o[vt][3] *= corr;
      }
    } else {
      lr += lloc;
    }

    // O^T += V^T * P^T (Pt read back in B-layout through the same swizzle)
    bf16x8 pa0 = *reinterpret_cast<const bf16x8*>(&PtW[fr * 64 + (quad ^ fx) * 8]);
    bf16x8 pa1 = *reinterpret_cast<const bf16x8*>(&PtW[fr * 64 + ((quad + 4) ^ fx) * 8]);
#pragma unroll
    for (int vt = 0; vt < 4; ++vt) {
      bf16x8 vb0 = *reinterpret_cast<const bf16x8*>(&Vcur[(vt * 16 + fr) * 64 + cA0]);
      bf16x8 vb1 = *reinterpret_cast<const bf16x8*>(&Vcur[(vt * 16 + fr) * 64 + cA1]);
      o[vt] = __builtin_amdgcn_mfma_f32_16x16x32_bf16(vb0, pa0, o[vt], 0, 0, 0);
      o[vt] = __builtin_amdgcn_mfma_f32_16x16x32_bf16(vb1, pa1, o[vt], 0, 0, 0);
    }
  }

  // epilogue: O^T[v][i=fr] / l_i -> concat bf16 [b,s,h*64]
  const float inv = (padi != 0 && lr > 0.f) ? 1.f / lr : 0.f;
  unsigned short* orow = concat + ((size_t)(b * SEQ + ir)) * DMODEL + h * HD;
#pragma unroll
  for (int vt = 0; vt < 4; ++vt) {
    uint2 pk;
    pk.x = pk2bf(o[vt][0] * inv, o[vt][1] * inv);
    pk.y = pk2bf(o[vt][2] * inv, o[vt][3] * inv);
    *reinterpret_cast<uint2*>(orow + vt * 16 + quad * 4) = pk;
  }
}

extern "C" void kernel_launch(void* const* d_in, const int* in_sizes, int n_in,
                              void* d_out, int out_size, void* d_ws, size_t ws_size,
                              hipStream_t stream) {
  (void)in_sizes; (void)n_in; (void)out_size;
  const float* x  = (const float*)d_in[0];
  const int* mask = (const int*)d_in[1];
  const float* Wq = (const float*)d_in[2];
  const float* bq = (const float*)d_in[3];
  const float* Wk = (const float*)d_in[4];
  const float* bk = (const float*)d_in[5];
  const float* Wv = (const float*)d_in[6];
  const float* bv = (const float*)d_in[7];
  const float* Wo = (const float*)d_in[8];
  const float* bo = (const float*)d_in[9];
  float* out = (float*)d_out;

  char* ws = (char*)d_ws;
  if (ws_size < (48ull << 20)) return;
  unsigned short* xb  = (unsigned short*)(ws);                 // 8 MB x bf16 [4096][1024]
  unsigned short* wqb = (unsigned short*)(ws + (8ull  << 20)); // wq|wk|wv contiguous ->
  unsigned short* wkb = (unsigned short*)(ws + (10ull << 20)); //   [3072][1024] B matrix
  unsigned short* wvb = (unsigned short*)(ws + (12ull << 20));
  unsigned short* wob = (unsigned short*)(ws + (14ull << 20));
  unsigned short* Qb  = (unsigned short*)(ws + (16ull << 20)); // 8 MB [b,h,s,64] (xscale)
  unsigned short* Kb  = (unsigned short*)(ws + (24ull << 20)); // 8 MB [b,h,s,64]
  unsigned short* Vtb = (unsigned short*)(ws + (32ull << 20)); // 8 MB [b,h,64,s]
  unsigned short* cb  = (unsigned short*)(ws + (40ull << 20)); // 8 MB concat bf16

  cast_all_kernel<<<4096, 256, 0, stream>>>(x, Wq, Wk, Wv, Wo, xb, wqb, wkb, wvb, wob);

  // fused QKV projection: B = [wq; wk; wv] = [3072][1024]
  gemm128<0><<<dim3(24, 32), 256, 0, stream>>>(xb, wqb, bq, bk, bv,
                                               nullptr, Qb, Kb, Vtb, 1024);

  attn_mfma_kernel<<<1024, 256, 0, stream>>>(Qb, Kb, Vtb, mask, cb);

  gemm128<1><<<dim3(8, 32), 256, 0, stream>>>(cb, wob, bo, nullptr, nullptr,
                                              out, nullptr, nullptr, nullptr, 1024);
}